// Round 9
// baseline (70.485 us; speedup 1.0000x reference)
//
#include <hip/hip_runtime.h>
#include <hip/hip_bf16.h>
#include <stdint.h>

typedef short bf16x8 __attribute__((ext_vector_type(8)));
typedef float f32x4 __attribute__((ext_vector_type(4)));

#define D  512
#define NB 4096
#define NT 8192

__device__ __forceinline__ unsigned short f2bf(float f) {
    __hip_bfloat16 h = __float2bfloat16(f);
    return *reinterpret_cast<unsigned short*>(&h);
}

// Fused fp32->bf16 convert + row squared-norm for BOTH inputs; x rows also
// write the fp32 passthrough (output 0). One wave per row. HBM-floor bound.
__global__ __launch_bounds__(256) void prep_kernel(
    const float* __restrict__ x, const float* __restrict__ y,
    unsigned short* __restrict__ xb, unsigned short* __restrict__ yb,
    float* __restrict__ x2, float* __restrict__ y2, float* __restrict__ copy)
{
    const int grow = blockIdx.x * 4 + (threadIdx.x >> 6);
    const int lane = threadIdx.x & 63;
    const bool isX = grow < NB;
    const int row  = isX ? grow : grow - NB;
    const float* src = isX ? x : y;
    unsigned short* dst = isX ? xb : yb;
    float* norms = isX ? x2 : y2;

    const float4* rp = reinterpret_cast<const float4*>(src + (size_t)row * D);
    float4 v0 = rp[lane * 2];
    float4 v1 = rp[lane * 2 + 1];
    if (isX) {
        float4* cp = reinterpret_cast<float4*>(copy + (size_t)row * D);
        cp[lane * 2]     = v0;
        cp[lane * 2 + 1] = v1;
    }
    float s = v0.x*v0.x + v0.y*v0.y + v0.z*v0.z + v0.w*v0.w
            + v1.x*v1.x + v1.y*v1.y + v1.z*v1.z + v1.w*v1.w;
    union { unsigned short h[8]; int4 v; } u;
    u.h[0] = f2bf(v0.x); u.h[1] = f2bf(v0.y); u.h[2] = f2bf(v0.z); u.h[3] = f2bf(v0.w);
    u.h[4] = f2bf(v1.x); u.h[5] = f2bf(v1.y); u.h[6] = f2bf(v1.z); u.h[7] = f2bf(v1.w);
    reinterpret_cast<int4*>(dst + (size_t)row * D)[lane] = u.v;
    #pragma unroll
    for (int off = 32; off > 0; off >>= 1) s += __shfl_xor(s, off);
    if (lane == 0) norms[row] = s;
}

// Persistent 512 blocks (2/CU), each computes 4 col-adjacent 128x128 tiles
// as ONE unified 64-K-tile pipeline (BK=32, 4 waves 2Mx2N, 3 rotating LDS
// buffers, counted vmcnt). Tile t's 64 sim values (transformed into VGPRs
// at its last K-tile) are stored 4 insts/K-tile spread across tile t+1's
// loop, issued FIFO-newest after the MFMA cluster; checkpoint vmcnt(8) =
// {newest stage 4 + newest stores 4}, so each store packet has a full
// K-tile to drain -> continuous store stream, MFMA hidden under it.
// LDS (ushort): buf b at b*8192: A 128x32 @+0, B 128x32 @+4096. 48 KiB.
__global__ __launch_bounds__(256, 2) void gemm_sim_kernel(
    const unsigned short* __restrict__ X, const unsigned short* __restrict__ Y,
    const float* __restrict__ x2, const float* __restrict__ y2,
    float* __restrict__ out)
{
    __shared__ alignas(16) unsigned short lds[24576];   // 48 KiB

    const int t    = threadIdx.x;
    const int lane = t & 63;
    const int w    = t >> 6;
    const int wr   = w >> 1;    // 0..1 (64 rows each)
    const int wc   = w & 1;     // 0..1 (64 cols each)

    // XCD map, L2-fit: per XCD 16 rowTiles x 4 colGroups
    // (A 16x128KB=2MB + B 4x1MB... 4x512x512x2B=2MB -> 4MB).
    const int bid = blockIdx.x;
    const int xcd = bid & 7;
    const int idx = bid >> 3;                           // 0..63
    const int rowBase = ((xcd & 1) * 16 + (idx & 15)) * 128;
    const int colBase = ((xcd >> 1) * 4 + (idx >> 4)) * 512;  // 4-tile group

    // Staging: thread t covers 16B at LDS ushort off t*8 (+2048 for rows 64+).
    // Chunk-XOR swizzle (rule #21): stored chunk c' = global chunk ^ ((row>>1)&3).
    const int swz = ((t & 3) ^ ((t >> 3) & 3)) * 8;
    const unsigned short* gA = X + (size_t)(rowBase + (t >> 2)) * D + swz;
    const unsigned short* gB = Y + (size_t)(colBase + (t >> 2)) * D + swz;

    // Read side: swizzle folds to a per-lane constant.
    const int cread = ((lane >> 4) ^ ((lane >> 1) & 3)) * 8;
    const int aoff = (wr * 64 + (lane & 15)) * 32 + cread;         // + buf + m*512
    const int boff = 4096 + (wc * 64 + (lane & 15)) * 32 + cread;  // + buf + n*512

    // Norms, preloaded once (rows/cols fixed per thread across all 4 tiles).
    float x2v[16], y2v[16];
    {
        const int r0 = rowBase + wr * 64 + ((lane >> 4) << 2);
        #pragma unroll
        for (int m = 0; m < 4; ++m)
            #pragma unroll
            for (int q = 0; q < 4; ++q)
                x2v[m * 4 + q] = x2[r0 + m * 16 + q];
        const int c0 = colBase + wc * 64 + (lane & 15);
        #pragma unroll
        for (int tl = 0; tl < 4; ++tl)
            #pragma unroll
            for (int n = 0; n < 4; ++n)
                y2v[tl * 4 + n] = y2[c0 + tl * 128 + n * 16];
    }
    float* outBase = out + (size_t)(rowBase + wr * 64 + ((lane >> 4) << 2)) * NT
                   + colBase + wc * 64 + (lane & 15);

    f32x4 acc[4][4] = {};
    f32x4 sim[4][4];
    bf16x8 a[4], b[4];

#define GLD(SRC, DST) __builtin_amdgcn_global_load_lds( \
    (const __attribute__((address_space(1))) void*)(SRC), \
    (__attribute__((address_space(3))) void*)(DST), 16, 0, 0)

#define STAGE(S) do { \
    GLD(gA + ((S) & 15) * 32,                           lds + ((S) % 3) * 8192 + t * 8); \
    GLD(gA + ((S) & 15) * 32 + 64 * D,                  lds + ((S) % 3) * 8192 + t * 8 + 2048); \
    GLD(gB + (size_t)((S) >> 4) * 128 * D + ((S) & 15) * 32,          lds + ((S) % 3) * 8192 + 4096 + t * 8); \
    GLD(gB + (size_t)((S) >> 4) * 128 * D + ((S) & 15) * 32 + 64 * D, lds + ((S) % 3) * 8192 + 4096 + t * 8 + 2048); \
} while (0)

// g = global K-step 0..63 (tile g>>4, kt g&15). All guards fold (g literal).
#define BODY(G) do { \
    _Pragma("unroll") \
    for (int m = 0; m < 4; ++m) a[m] = *(const bf16x8*)(lds + ((G) % 3) * 8192 + aoff + m * 512); \
    _Pragma("unroll") \
    for (int n = 0; n < 4; ++n) b[n] = *(const bf16x8*)(lds + ((G) % 3) * 8192 + boff + n * 512); \
    if ((G) + 2 <= 63) STAGE((G) + 2); \
    __builtin_amdgcn_s_barrier(); \
    asm volatile("s_waitcnt lgkmcnt(0)" ::: "memory"); \
    __builtin_amdgcn_s_setprio(1); \
    _Pragma("unroll") \
    for (int m = 0; m < 4; ++m) \
        _Pragma("unroll") \
        for (int n = 0; n < 4; ++n) \
            acc[m][n] = __builtin_amdgcn_mfma_f32_16x16x32_bf16(a[m], b[n], acc[m][n], 0, 0, 0); \
    __builtin_amdgcn_s_setprio(0); \
    if ((G) >= 16) { \
        _Pragma("unroll") \
        for (int i = 0; i < 4; ++i) { \
            const int si = ((G) & 15) * 4 + i; \
            const int mi = si >> 4, q = (si >> 2) & 3, n = si & 3; \
            outBase[(size_t)(mi * 16 + q) * NT + (((G) >> 4) - 1) * 128 + n * 16] = sim[mi][n][q]; \
        } \
    } \
    if (((G) & 15) == 15) { \
        _Pragma("unroll") \
        for (int m = 0; m < 4; ++m) \
            _Pragma("unroll") \
            for (int n = 0; n < 4; ++n) { \
                _Pragma("unroll") \
                for (int q = 0; q < 4; ++q) { \
                    float sq = fmaxf(x2v[m * 4 + q] + y2v[((G) >> 4) * 4 + n] - 2.0f * acc[m][n][q], 0.0f); \
                    sim[m][n][q] = fminf(rsqrtf(sq), 1.0e6f); \
                } \
                acc[m][n] = (f32x4){0.f, 0.f, 0.f, 0.f}; \
            } \
    } \
    if ((G) <= 15)      { asm volatile("s_waitcnt vmcnt(4)" ::: "memory"); } \
    else if ((G) <= 62) { asm volatile("s_waitcnt vmcnt(8)" ::: "memory"); } \
    if ((G) < 63) __builtin_amdgcn_s_barrier(); \
} while (0)

    // Prologue: g=0 and g=1 staged (8 loads); vmcnt(4) -> g=0 landed.
    STAGE(0); STAGE(1);
    asm volatile("s_waitcnt vmcnt(4)" ::: "memory");
    __builtin_amdgcn_s_barrier();

#define B2(G) BODY(G); BODY((G) + 1);
#define B8(G) B2(G) B2((G) + 2) B2((G) + 4) B2((G) + 6)
    B8(0) B8(8) B8(16) B8(24) B8(32) B8(40) B8(48) B8(56)
#undef B8
#undef B2
#undef BODY
#undef STAGE
#undef GLD

    // Tail: tile 3's 64 stores (33.5 MB chip-wide).
    #pragma unroll
    for (int si = 0; si < 64; ++si) {
        const int mi = si >> 4, q = (si >> 2) & 3, n = si & 3;
        outBase[(size_t)(mi * 16 + q) * NT + 3 * 128 + n * 16] = sim[mi][n][q];
    }
}

extern "C" void kernel_launch(void* const* d_in, const int* in_sizes, int n_in,
                              void* d_out, int out_size, void* d_ws, size_t ws_size,
                              hipStream_t stream)
{
    const float* x = (const float*)d_in[0];
    const float* y = (const float*)d_in[1];
    float* out = (float*)d_out;
    char* ws = (char*)d_ws;

    unsigned short* xb = (unsigned short*)ws;                 // 4 MB
    unsigned short* yb = (unsigned short*)(ws + (4u << 20));  // 8 MB
    float* x2 = (float*)(ws + (12u << 20));                   // 16 KB
    float* y2 = (float*)(ws + (12u << 20) + 4 * NB);          // 32 KB

    prep_kernel<<<(NB + NT) / 4, 256, 0, stream>>>(x, y, xb, yb, x2, y2, out);
    gemm_sim_kernel<<<512, 256, 0, stream>>>(xb, yb, x2, y2, out + (size_t)NB * D);
}

// Round 10
// 60.596 us; speedup vs baseline: 1.1632x; 1.1632x over previous
//
#include <hip/hip_runtime.h>
#include <hip/hip_bf16.h>
#include <stdint.h>

typedef short bf16x8 __attribute__((ext_vector_type(8)));
typedef float f32x4 __attribute__((ext_vector_type(4)));

#define D  512
#define NB 4096
#define NT 8192

__device__ __forceinline__ unsigned short f2bf(float f) {
    __hip_bfloat16 h = __float2bfloat16(f);
    return *reinterpret_cast<unsigned short*>(&h);
}

// Fused fp32->bf16 convert + row squared-norm for BOTH inputs; x rows also
// write the fp32 passthrough (output 0). One wave per row. HBM-floor bound.
__global__ __launch_bounds__(256) void prep_kernel(
    const float* __restrict__ x, const float* __restrict__ y,
    unsigned short* __restrict__ xb, unsigned short* __restrict__ yb,
    float* __restrict__ x2, float* __restrict__ y2, float* __restrict__ copy)
{
    const int grow = blockIdx.x * 4 + (threadIdx.x >> 6);
    const int lane = threadIdx.x & 63;
    const bool isX = grow < NB;
    const int row  = isX ? grow : grow - NB;
    const float* src = isX ? x : y;
    unsigned short* dst = isX ? xb : yb;
    float* norms = isX ? x2 : y2;

    const float4* rp = reinterpret_cast<const float4*>(src + (size_t)row * D);
    float4 v0 = rp[lane * 2];
    float4 v1 = rp[lane * 2 + 1];
    if (isX) {
        float4* cp = reinterpret_cast<float4*>(copy + (size_t)row * D);
        cp[lane * 2]     = v0;
        cp[lane * 2 + 1] = v1;
    }
    float s = v0.x*v0.x + v0.y*v0.y + v0.z*v0.z + v0.w*v0.w
            + v1.x*v1.x + v1.y*v1.y + v1.z*v1.z + v1.w*v1.w;
    union { unsigned short h[8]; int4 v; } u;
    u.h[0] = f2bf(v0.x); u.h[1] = f2bf(v0.y); u.h[2] = f2bf(v0.z); u.h[3] = f2bf(v0.w);
    u.h[4] = f2bf(v1.x); u.h[5] = f2bf(v1.y); u.h[6] = f2bf(v1.z); u.h[7] = f2bf(v1.w);
    reinterpret_cast<int4*>(dst + (size_t)row * D)[lane] = u.v;
    #pragma unroll
    for (int off = 32; off > 0; off >>= 1) s += __shfl_xor(s, off);
    if (lane == 0) norms[row] = s;
}

// 128x256 tile, BK=32, 4 waves (1Mx4N, wave-tile 128x64), 3 rotating LDS
// buffers. SINGLE barrier + single vmcnt per K-tile, NO explicit lgkm
// drains: frags are C++ ds_reads consumed by the 32-MFMA cluster before
// the barrier (compiler inserts fine-grained lgkm waits), so read
// retirement is implicit; the one barrier then publishes (a) read
// retirement for write-after-read vs. the stage of buf[(kt+2)%3] (last
// read at kt-1), and (b) staged-data landing (pre-barrier vmcnt(6) ckpt
// = kt+1's 6 loads landed, kt+2's 6 still in flight). sched_barrier(0)
// pins the cluster before the raw s_barrier (rule-18 insurance).
// LDS (ushort): buf b at b*12288: A 128x32 @+0 (8 KB), B 256x32 @+4096
// (16 KB). 72 KiB total -> 2 blocks/CU co-resident.
__global__ __launch_bounds__(256, 2) void gemm_sim_kernel(
    const unsigned short* __restrict__ X, const unsigned short* __restrict__ Y,
    const float* __restrict__ x2, const float* __restrict__ y2,
    float* __restrict__ out)
{
    __shared__ alignas(16) unsigned short lds[36864];   // 72 KiB

    const int t    = threadIdx.x;
    const int lane = t & 63;
    const int w    = t >> 6;          // 0..3, wave col (64 cols each)

    // XCD swizzle, L2-fit: each XCD covers 16 rowTiles x 8 colTiles
    // (A 2 MB + B 2 MB = 4 MB = per-XCD L2).
    const int bid = blockIdx.x;
    const int xcd = bid & 7;
    const int idx = bid >> 3;                          // 0..127
    const int rowBase = ((xcd >> 2) * 16 + (idx & 15)) * 128;
    const int colBase = ((xcd & 3) * 8 + (idx >> 4)) * 256;

    // Staging: thread t writes 16 B chunks at LDS ushort off t*8 (+L*2048).
    // Chunk-XOR swizzle (rule #21): stored chunk c' holds global chunk
    // c' ^ ((row>>1)&3); folds to t-only constants for all L.
    const int swz = ((t & 3) ^ ((t >> 3) & 3)) * 8;
    const unsigned short* gA = X + (size_t)(rowBase + (t >> 2)) * D + swz;
    const unsigned short* gB = Y + (size_t)(colBase + (t >> 2)) * D + swz;

    // Read side: swizzle folds to a per-lane constant.
    const int cread = ((lane >> 4) ^ ((lane >> 1) & 3)) * 8;
    const int aoff = (lane & 15) * 32 + cread;                    // + buf + h*2048 + m*512
    const int boff = 4096 + (w * 64 + (lane & 15)) * 32 + cread;  // + buf + n*512

    f32x4 acc[8][4] = {};

#define STAGE_A(BUF, KT) do { \
    _Pragma("unroll") \
    for (int L = 0; L < 2; ++L) \
        __builtin_amdgcn_global_load_lds( \
            (const __attribute__((address_space(1))) void*)(gA + (size_t)L * 64 * D + (KT) * 32), \
            (__attribute__((address_space(3))) void*)(lds + (BUF) * 12288 + t * 8 + L * 2048), 16, 0, 0); \
} while (0)

#define STAGE_B(BUF, KT) do { \
    _Pragma("unroll") \
    for (int L = 0; L < 4; ++L) \
        __builtin_amdgcn_global_load_lds( \
            (const __attribute__((address_space(1))) void*)(gB + (size_t)L * 64 * D + (KT) * 32), \
            (__attribute__((address_space(3))) void*)(lds + (BUF) * 12288 + 4096 + t * 8 + L * 2048), 16, 0, 0); \
} while (0)

    // Prologue: kt0 + kt1 staged (12 loads); vmcnt(6) -> kt0 landed.
    STAGE_A(0, 0); STAGE_B(0, 0);
    STAGE_A(1, 1); STAGE_B(1, 1);
    asm volatile("s_waitcnt vmcnt(6)" ::: "memory");
    __builtin_amdgcn_s_barrier();

    // 16 K-tiles, buffer = kt%3, ONE merged phase per kt.
#pragma unroll
    for (int kt = 0; kt < 16; ++kt) {
        bf16x8 _a[2][4], _b[4];
        #pragma unroll
        for (int n = 0; n < 4; ++n)
            _b[n] = *(const bf16x8*)(lds + (kt % 3) * 12288 + boff + n * 512);
        #pragma unroll
        for (int h = 0; h < 2; ++h)
            #pragma unroll
            for (int m = 0; m < 4; ++m)
                _a[h][m] = *(const bf16x8*)(lds + (kt % 3) * 12288 + aoff + h * 2048 + m * 512);
        if (kt + 2 < 16) {
            STAGE_A(((kt + 2) % 3), kt + 2);
            STAGE_B(((kt + 2) % 3), kt + 2);
        }
        __builtin_amdgcn_s_setprio(1);
        #pragma unroll
        for (int h = 0; h < 2; ++h)
            #pragma unroll
            for (int m = 0; m < 4; ++m)
                #pragma unroll
                for (int n = 0; n < 4; ++n)
                    acc[h * 4 + m][n] = __builtin_amdgcn_mfma_f32_16x16x32_bf16(
                        _a[h][m], _b[n], acc[h * 4 + m][n], 0, 0, 0);
        __builtin_amdgcn_s_setprio(0);
        __builtin_amdgcn_sched_barrier(0);
        if (kt < 14)       { asm volatile("s_waitcnt vmcnt(6)" ::: "memory"); }
        else if (kt == 14) { asm volatile("s_waitcnt vmcnt(0)" ::: "memory"); }
        if (kt < 15) __builtin_amdgcn_s_barrier();
    }
#undef STAGE_A
#undef STAGE_B

    // Epilogue: C/D layout col = lane&15, row = (lane>>4)*4 + reg.
    const int col0 = colBase + w * 64 + (lane & 15);
    const int row0 = rowBase + ((lane >> 4) << 2);
    #pragma unroll
    for (int mi = 0; mi < 8; ++mi) {
        const int rbase = row0 + (mi >> 2) * 64 + (mi & 3) * 16;
        #pragma unroll
        for (int q = 0; q < 4; ++q) {
            const int grow = rbase + q;
            const float xn = x2[grow];
            float* orow = out + (size_t)grow * NT;
            #pragma unroll
            for (int n = 0; n < 4; ++n) {
                const int gcol = col0 + n * 16;
                float sq = fmaxf(xn + y2[gcol] - 2.0f * acc[mi][n][q], 0.0f);
                orow[gcol] = fminf(rsqrtf(sq), 1.0e6f);  // rsqrt(0)=inf -> clipped
            }
        }
    }
}

extern "C" void kernel_launch(void* const* d_in, const int* in_sizes, int n_in,
                              void* d_out, int out_size, void* d_ws, size_t ws_size,
                              hipStream_t stream)
{
    const float* x = (const float*)d_in[0];
    const float* y = (const float*)d_in[1];
    float* out = (float*)d_out;
    char* ws = (char*)d_ws;

    unsigned short* xb = (unsigned short*)ws;                 // 4 MB
    unsigned short* yb = (unsigned short*)(ws + (4u << 20));  // 8 MB
    float* x2 = (float*)(ws + (12u << 20));                   // 16 KB
    float* y2 = (float*)(ws + (12u << 20) + 4 * NB);          // 32 KB

    prep_kernel<<<(NB + NT) / 4, 256, 0, stream>>>(x, y, xb, yb, x2, y2, out);
    gemm_sim_kernel<<<1024, 256, 0, stream>>>(xb, yb, x2, y2, out + (size_t)NB * D);
}